// Round 12
// baseline (103.528 us; speedup 1.0000x reference)
//
#include <hip/hip_runtime.h>

// UpsampleRFFT (zero-insert 2x + ideal half-band low-pass, circular), closed form:
//   g[j] = sign*cot(pi*(2j+1)/256)/128, sign=+ if j even
//   out[2r][2i]   = x[r][i] (exact fp32)      out[2r][2i+1] = T[r][i],  T = X*G
//   out[2p+1][c]  = sum_m g[(p-m)&127] * E[m][c],  E = even rows
// 2 blocks per image (output-column halves), LDS = 34.8KB -> 4 blocks/CU.
// Phase A: T via MFMA (row-resident X), even rows stored in-loop, E^T (bf16) to
// LDS. Phase B: odd = G*E from LDS E^T.
//
// R5-R7 lesson (rule #20): runtime-indexed register arrays -> scratch. All frag
// indices compile-time; runtime offsets (cb, w) folded into LOAD ADDRESSES.
// R10 lesson: nontemporal stores hurt (partial-line HBM RMW); deferred stores
// not needed. R11 lesson: XCD pairing neutral (x is L3-resident anyway).
// R12: manual 4-op integer-RNE f2bf (~190 VALU/thread) -> native (__bf16)
// casts (v_cvt_pk_bf16_f32, ~1 op/value); constant-index vector inserts keep
// everything register-resident.

typedef __bf16 bf16x8 __attribute__((ext_vector_type(8)));
typedef float  f32x4  __attribute__((ext_vector_type(4)));

#define W2 136        // Et pitch in bf16: 272B rows, 16B-aligned
#define PI_F 3.14159265358979323846f

__device__ __forceinline__ unsigned short f2bf(float x) {
    unsigned int b = __float_as_uint(x);
    return (unsigned short)((b + 0x7FFFu + ((b >> 16) & 1u)) >> 16);  // RNE
}

__device__ __forceinline__ float gfun(int j) {           // g[j & 127]
    int d = 2 * (j & 127) + 1;
    float th = PI_F * (float)d * (1.0f / 256.0f);
    float s  = ((d & 3) == 1) ? 1.0f : -1.0f;
    return s * cosf(th) / (128.0f * sinf(th));
}

// ---- init: per-lane tap fragment table (8 frags x 64 lanes x 8 bf16 = 8KB) ----
__global__ __launch_bounds__(512)
void init_ghtab(unsigned short* __restrict__ ghtab)
{
    const int t    = threadIdx.x;         // t = dd*64 + lane
    const int lane = t & 63;
    const int l15  = lane & 15;
    const int l4   = lane >> 4;
    const int dd   = t >> 6;
    const int base = l15 - 8 * l4 + 16 * dd;
    unsigned short u[8];
    #pragma unroll
    for (int e = 0; e < 8; ++e) u[e] = f2bf(gfun(base - e));
    *(ushort4*)&ghtab[t * 8]     = make_ushort4(u[0], u[1], u[2], u[3]);
    *(ushort4*)&ghtab[t * 8 + 4] = make_ushort4(u[4], u[5], u[6], u[7]);
}

// ---- fused kernel: 2 blocks/image (c-halves), 512 threads (8 waves) ----
__global__ __launch_bounds__(512, 4)
void upsample_fused(const float* __restrict__ xin, float* __restrict__ out,
                    const unsigned short* __restrict__ ghtab)
{
    __shared__ __align__(16) __bf16 Et[128 * W2];  // Et[c_loc][r]

    const int tid  = threadIdx.x;
    const int lane = tid & 63;
    const int w    = tid >> 6;        // 0..7: r-tile (A) and p-tile (B)
    const int l15  = lane & 15;
    const int l4   = lane >> 4;

    const long long img = blockIdx.x >> 1;
    const int cb        = blockIdx.x & 1;          // column half
    const float* __restrict__ xim = xin + img * (128LL * 128LL);
    float*       __restrict__ oim = out + img * (256LL * 256LL);

    const int r = 16 * w + l15;
    const float* __restrict__ xrow = xim + r * 128;

    // issue full-row x loads first (K=128 needed for the W-conv)
    float4 xlo[4], xhi[4];
    #pragma unroll
    for (int t = 0; t < 4; ++t) {
        xlo[t] = *(const float4*)&xrow[32 * t + 8 * l4];
        xhi[t] = *(const float4*)&xrow[32 * t + 8 * l4 + 4];
    }

    // Phase-A tap frags: cb folded into the ADDRESS; register indices static.
    // ghc[v] = frag[(v + 4cb) & 7].
    bf16x8 ghc[8];
    #pragma unroll
    for (int v = 0; v < 8; ++v) {
        const int dd = (v + 4 * cb) & 7;
        ghc[v] = *(const bf16x8*)&ghtab[(dd * 64 + lane) * 8];
    }

    // X fragments: native v_cvt_pk_bf16_f32 casts, constant-index vector
    // inserts (register-resident). Even cols of E^T written in the same pass.
    bf16x8 xa[4];
    #pragma unroll
    for (int t = 0; t < 4; ++t) {
        bf16x8 a;
        a[0] = (__bf16)xlo[t].x; a[1] = (__bf16)xlo[t].y;
        a[2] = (__bf16)xlo[t].z; a[3] = (__bf16)xlo[t].w;
        a[4] = (__bf16)xhi[t].x; a[5] = (__bf16)xhi[t].y;
        a[6] = (__bf16)xhi[t].z; a[7] = (__bf16)xhi[t].w;
        xa[t] = a;
        if ((t >> 1) == cb) {                      // this t covers our c-half
            const int tt = t & 1;
            #pragma unroll
            for (int e = 0; e < 8; ++e)
                Et[(64 * tt + 16 * l4 + 2 * e) * W2 + r] = a[e];
        }
    }

    // ---- phase A: T = X*G (transposed); even output rows + odd cols of E^T ----
    float* __restrict__ orow = oim + (2 * r) * 256 + 128 * cb;
    #pragma unroll
    for (int mt = 0; mt < 4; ++mt) {
        f32x4 acc = {0.f, 0.f, 0.f, 0.f};
        #pragma unroll
        for (int t = 0; t < 4; ++t)
            acc = __builtin_amdgcn_mfma_f32_16x16x32_bf16(ghc[(mt - 2 * t) & 7],
                                                          xa[t], acc, 0, 0, 0);
        const int i0l = 16 * mt + 4 * l4;          // local i in [0,64)
        float4 xc = *(const float4*)&xrow[64 * cb + i0l];   // L1 hit, exact fp32
        float4 o0 = make_float4(xc.x, acc[0], xc.y, acc[1]);
        float4 o1 = make_float4(xc.z, acc[2], xc.w, acc[3]);
        *(float4*)&orow[2 * i0l]     = o0;
        *(float4*)&orow[2 * i0l + 4] = o1;
        #pragma unroll
        for (int q = 0; q < 4; ++q)
            Et[(2 * (i0l + q) + 1) * W2 + r] = (__bf16)acc[q];
    }
    __syncthreads();

    // ---- phase B: odd[p][c] = sum_m g[(p-m)&127] * E[m][c] ----
    {
        // Per-wave B-frags loaded at runtime-computed ADDRESSES (indices static).
        bf16x8 gb[4];
        #pragma unroll
        for (int t = 0; t < 4; ++t) {
            const int dd = (w - 2 * t) & 7;
            gb[t] = *(const bf16x8*)&ghtab[(dd * 64 + lane) * 8];
        }
        float* __restrict__ prow = oim + (2 * (16 * w + l15) + 1) * 256 + 128 * cb;
        #pragma unroll
        for (int mc = 0; mc < 8; ++mc) {
            f32x4 acc = {0.f, 0.f, 0.f, 0.f};
            #pragma unroll
            for (int t = 0; t < 4; ++t) {
                bf16x8 ef = *(const bf16x8*)&Et[(16 * mc + l15) * W2 + 32 * t + 8 * l4];
                acc = __builtin_amdgcn_mfma_f32_16x16x32_bf16(ef, gb[t], acc, 0, 0, 0);
            }
            float4 o = make_float4(acc[0], acc[1], acc[2], acc[3]);
            *(float4*)&prow[16 * mc + 4 * l4] = o;   // p=16w+l15, c=16mc+4l4+q
        }
    }
}

extern "C" void kernel_launch(void* const* d_in, const int* in_sizes, int n_in,
                              void* d_out, int out_size, void* d_ws, size_t ws_size,
                              hipStream_t stream)
{
    (void)n_in; (void)out_size; (void)ws_size;
    const float* x = (const float*)d_in[0];
    float* out = (float*)d_out;
    int nimg = in_sizes[0] / (128 * 128);   // 1024 images

    unsigned short* ghtab = (unsigned short*)d_ws;   // needs 8KB; ws is ample
    hipLaunchKernelGGL(init_ghtab, dim3(1), dim3(512), 0, stream, ghtab);
    hipLaunchKernelGGL(upsample_fused, dim3(nimg * 2), dim3(512), 0, stream, x, out, ghtab);
}

// Round 13
// 95.355 us; speedup vs baseline: 1.0857x; 1.0857x over previous
//
#include <hip/hip_runtime.h>

// UpsampleRFFT (zero-insert 2x + ideal half-band low-pass, circular), closed form:
//   g[j] = sign*cot(pi*(2j+1)/256)/128, sign=+ if j even
//   out[2r][2i]   = x[r][i] (exact fp32)      out[2r][2i+1] = T[r][i],  T = X*G
//   out[2p+1][c]  = sum_m g[(p-m)&127] * E[m][c],  E = even rows
// 2 blocks per image (output-column halves), LDS = 32KB -> 4 blocks/CU.
//
// R5-R7 (rule #20): runtime-indexed register arrays -> scratch; all frag
// indices compile-time, runtime offsets folded into LOAD ADDRESSES.
// R10: nontemporal stores hurt. R11: XCD pairing neutral. R12: native casts
// neutral -> keep R8's manual f2bf body.
// R13: (a) Et pitch 128 + XOR swizzle (pitch 272B made rows 8 apart alias the
// same banks -> 4-8-way conflicts on phase-A scalar writes, 3.1M conflict cyc);
// swizzle applied identically on write & read, bijective within each 256B row.
// (b) phase-B 2-p-tile reuse: each ef ds_read feeds 2 MFMAs -> reads halve.

typedef __bf16 bf16x8 __attribute__((ext_vector_type(8)));
typedef float  f32x4  __attribute__((ext_vector_type(4)));

#define PI_F 3.14159265358979323846f

__device__ __forceinline__ unsigned short f2bf(float x) {
    unsigned int b = __float_as_uint(x);
    return (unsigned short)((b + 0x7FFFu + ((b >> 16) & 1u)) >> 16);  // RNE
}

__device__ __forceinline__ float gfun(int j) {           // g[j & 127]
    int d = 2 * (j & 127) + 1;
    float th = PI_F * (float)d * (1.0f / 256.0f);
    float s  = ((d & 3) == 1) ? 1.0f : -1.0f;
    return s * cosf(th) / (128.0f * sinf(th));
}

// byte-offset XOR swizzle within a 256B Et row (bits 4..6); same fn on W+R.
__device__ __forceinline__ int etswz(int row) {
    return (((row & 7) ^ (((row >> 3) & 3) << 1) ^ (((row >> 5) & 1) << 2)) << 4);
}

// ---- init: per-lane tap fragment table (8 frags x 64 lanes x 8 bf16 = 8KB) ----
__global__ __launch_bounds__(512)
void init_ghtab(unsigned short* __restrict__ ghtab)
{
    const int t    = threadIdx.x;         // t = dd*64 + lane
    const int lane = t & 63;
    const int l15  = lane & 15;
    const int l4   = lane >> 4;
    const int dd   = t >> 6;
    const int base = l15 - 8 * l4 + 16 * dd;
    unsigned short u[8];
    #pragma unroll
    for (int e = 0; e < 8; ++e) u[e] = f2bf(gfun(base - e));
    *(ushort4*)&ghtab[t * 8]     = make_ushort4(u[0], u[1], u[2], u[3]);
    *(ushort4*)&ghtab[t * 8 + 4] = make_ushort4(u[4], u[5], u[6], u[7]);
}

// ---- fused kernel: 2 blocks/image (c-halves), 512 threads (8 waves) ----
__global__ __launch_bounds__(512, 4)
void upsample_fused(const float* __restrict__ xin, float* __restrict__ out,
                    const unsigned short* __restrict__ ghtab)
{
    __shared__ __align__(16) unsigned short Et[128 * 128]; // Et[c_loc][m], swizzled

    const int tid  = threadIdx.x;
    const int lane = tid & 63;
    const int w    = tid >> 6;        // 0..7: r-tile (A); (pa,mh) in phase B
    const int l15  = lane & 15;
    const int l4   = lane >> 4;

    const long long img = blockIdx.x >> 1;
    const int cb        = blockIdx.x & 1;          // column half
    const float* __restrict__ xim = xin + img * (128LL * 128LL);
    float*       __restrict__ oim = out + img * (256LL * 256LL);

    const int r = 16 * w + l15;
    const float* __restrict__ xrow = xim + r * 128;

    // issue full-row x loads first (K=128 needed for the W-conv)
    float4 xlo[4], xhi[4];
    #pragma unroll
    for (int t = 0; t < 4; ++t) {
        xlo[t] = *(const float4*)&xrow[32 * t + 8 * l4];
        xhi[t] = *(const float4*)&xrow[32 * t + 8 * l4 + 4];
    }

    // Phase-A tap frags: cb folded into the ADDRESS; register indices static.
    bf16x8 ghc[8];
    #pragma unroll
    for (int v = 0; v < 8; ++v) {
        const int dd = (v + 4 * cb) & 7;
        ghc[v] = *(const bf16x8*)&ghtab[(dd * 64 + lane) * 8];
    }

    // X fragments (transient union, register-resident) + even cols of E^T.
    bf16x8 xa[4];
    #pragma unroll
    for (int t = 0; t < 4; ++t) {
        union { bf16x8 v; unsigned short u[8]; } H;
        H.u[0] = f2bf(xlo[t].x); H.u[1] = f2bf(xlo[t].y);
        H.u[2] = f2bf(xlo[t].z); H.u[3] = f2bf(xlo[t].w);
        H.u[4] = f2bf(xhi[t].x); H.u[5] = f2bf(xhi[t].y);
        H.u[6] = f2bf(xhi[t].z); H.u[7] = f2bf(xhi[t].w);
        xa[t] = H.v;
        if ((t >> 1) == cb) {                      // this t covers our c-half
            const int tt = t & 1;
            #pragma unroll
            for (int e = 0; e < 8; ++e) {
                const int row = 64 * tt + 16 * l4 + 2 * e;
                Et[row * 128 + (((2 * r) ^ etswz(row)) >> 1)] = H.u[e];
            }
        }
    }

    // ---- phase A: T = X*G (transposed); even output rows + odd cols of E^T ----
    float* __restrict__ orow = oim + (2 * r) * 256 + 128 * cb;
    #pragma unroll
    for (int mt = 0; mt < 4; ++mt) {
        f32x4 acc = {0.f, 0.f, 0.f, 0.f};
        #pragma unroll
        for (int t = 0; t < 4; ++t)
            acc = __builtin_amdgcn_mfma_f32_16x16x32_bf16(ghc[(mt - 2 * t) & 7],
                                                          xa[t], acc, 0, 0, 0);
        const int i0l = 16 * mt + 4 * l4;          // local i in [0,64)
        float4 xc = *(const float4*)&xrow[64 * cb + i0l];   // L1 hit, exact fp32
        float4 o0 = make_float4(xc.x, acc[0], xc.y, acc[1]);
        float4 o1 = make_float4(xc.z, acc[2], xc.w, acc[3]);
        *(float4*)&orow[2 * i0l]     = o0;
        *(float4*)&orow[2 * i0l + 4] = o1;
        #pragma unroll
        for (int q = 0; q < 4; ++q) {
            const int row = 2 * (i0l + q) + 1;
            Et[row * 128 + (((2 * r) ^ etswz(row)) >> 1)] = f2bf(acc[q]);
        }
    }
    __syncthreads();

    // ---- phase B: odd[p][c] = sum_m g[(p-m)&127] * E[m][c]
    //      2-p-tile reuse: wave -> p-tiles {pa, pa+4}, mc range 4*mh..4*mh+3 ----
    {
        const int pa = w & 3;
        const int mh = w >> 2;
        // 4 tap frags cover both p-tiles: gbd[d] = frag[(pa+2d)&7].
        bf16x8 gbd[4];
        #pragma unroll
        for (int d = 0; d < 4; ++d) {
            const int dd = (pa + 2 * d) & 7;
            gbd[d] = *(const bf16x8*)&ghtab[(dd * 64 + lane) * 8];
        }
        float* __restrict__ prowA = oim + (2 * (16 * pa + l15) + 1) * 256 + 128 * cb;
        float* __restrict__ prowB = oim + (2 * (16 * (pa + 4) + l15) + 1) * 256 + 128 * cb;
        #pragma unroll
        for (int mci = 0; mci < 4; ++mci) {
            const int mc = 4 * mh + mci;
            const int row = 16 * mc + l15;
            const char* erow = (const char*)Et + row * 256;
            const int sw = etswz(row);
            f32x4 aA = {0.f, 0.f, 0.f, 0.f};
            f32x4 aB = {0.f, 0.f, 0.f, 0.f};
            #pragma unroll
            for (int t = 0; t < 4; ++t) {
                bf16x8 ef = *(const bf16x8*)(erow + (((64 * t + 16 * l4)) ^ sw));
                // pa:   dd=(pa-2t)&7   -> d=(-t)&3 ; pa+4: dd=(pa+4-2t)&7 -> d=(2-t)&3
                aA = __builtin_amdgcn_mfma_f32_16x16x32_bf16(ef, gbd[(-t) & 3], aA, 0, 0, 0);
                aB = __builtin_amdgcn_mfma_f32_16x16x32_bf16(ef, gbd[(2 - t) & 3], aB, 0, 0, 0);
            }
            float4 oA = make_float4(aA[0], aA[1], aA[2], aA[3]);
            float4 oB = make_float4(aB[0], aB[1], aB[2], aB[3]);
            *(float4*)&prowA[16 * mc + 4 * l4] = oA;
            *(float4*)&prowB[16 * mc + 4 * l4] = oB;
        }
    }
}

extern "C" void kernel_launch(void* const* d_in, const int* in_sizes, int n_in,
                              void* d_out, int out_size, void* d_ws, size_t ws_size,
                              hipStream_t stream)
{
    (void)n_in; (void)out_size; (void)ws_size;
    const float* x = (const float*)d_in[0];
    float* out = (float*)d_out;
    int nimg = in_sizes[0] / (128 * 128);   // 1024 images

    unsigned short* ghtab = (unsigned short*)d_ws;   // needs 8KB; ws is ample
    hipLaunchKernelGGL(init_ghtab, dim3(1), dim3(512), 0, stream, ghtab);
    hipLaunchKernelGGL(upsample_fused, dim3(nimg * 2), dim3(512), 0, stream, x, out, ghtab);
}